// Round 1
// baseline (199.269 us; speedup 1.0000x reference)
//
#include <hip/hip_runtime.h>
#include <hip/hip_bf16.h>

// Problem constants (fixed by the reference): B=16, V=8192, N=2048, H=128, C_OUT=7
#define B_GR   16
#define V_PTS  8192
#define N_RES  2048
#define H_DIM  128
#define C_OUT  7
#define SEGS   16            // pool kernel: residue segments per graph (128 residues each)

// ---------------------------------------------------------------------------
// Kernel 1: per-vertex nearest-residue argmin.
// Replicates the reference's fp32 arithmetic exactly:
//   d = (|v|^2 - 2*(v.c)) + |c|^2, argmin over n, first index wins ties.
// Grid: B_GR * (V_PTS/512) = 256 blocks, 256 threads, 2 vertices/thread.
// Coords staged in LDS as float4{x,y,z,|c|^2} -> 1 ds_read_b128 / residue.
// ---------------------------------------------------------------------------
__global__ __launch_bounds__(256) void k_argmin(const float* __restrict__ verts,
                                                const float* __restrict__ coords,
                                                int* __restrict__ mi) {
    __shared__ float4 sc[N_RES];                       // 32 KB
    const int blocksPerGraph = V_PTS / 512;            // 16
    const int b   = blockIdx.x / blocksPerGraph;
    const int blk = blockIdx.x % blocksPerGraph;

    const float* cbase = coords + (size_t)b * N_RES * 3;
    for (int i = threadIdx.x; i < N_RES; i += 256) {
        float x = cbase[i * 3 + 0];
        float y = cbase[i * 3 + 1];
        float z = cbase[i * 3 + 2];
        // |c|^2 in the reference's order: (x*x + y*y) + z*z, round-to-nearest each op
        float csq = __fadd_rn(__fadd_rn(__fmul_rn(x, x), __fmul_rn(y, y)), __fmul_rn(z, z));
        sc[i] = make_float4(x, y, z, csq);
    }
    __syncthreads();

    const float* vbase = verts + (size_t)b * V_PTS * 3;
    const int v0 = blk * 512 + threadIdx.x;
    const int v1 = v0 + 256;

    const float x0 = vbase[v0 * 3 + 0], y0 = vbase[v0 * 3 + 1], z0 = vbase[v0 * 3 + 2];
    const float x1 = vbase[v1 * 3 + 0], y1 = vbase[v1 * 3 + 1], z1 = vbase[v1 * 3 + 2];
    const float vsq0 = __fadd_rn(__fadd_rn(__fmul_rn(x0, x0), __fmul_rn(y0, y0)), __fmul_rn(z0, z0));
    const float vsq1 = __fadd_rn(__fadd_rn(__fmul_rn(x1, x1), __fmul_rn(y1, y1)), __fmul_rn(z1, z1));

    float best0 = 3.402823466e+38f, best1 = 3.402823466e+38f;
    int   bi0 = 0, bi1 = 0;

#pragma unroll 4
    for (int n = 0; n < N_RES; ++n) {
        const float4 c = sc[n];
        // dot = (x*cx + y*cy) + z*cz, plain RN ops (no contraction)
        float dot0 = __fadd_rn(__fadd_rn(__fmul_rn(x0, c.x), __fmul_rn(y0, c.y)), __fmul_rn(z0, c.z));
        float dot1 = __fadd_rn(__fadd_rn(__fmul_rn(x1, c.x), __fmul_rn(y1, c.y)), __fmul_rn(z1, c.z));
        // fmaf(-2,dot,vsq) == RN(vsq - 2*dot) exactly (2*dot is exact)
        float d0 = __fadd_rn(fmaf(-2.0f, dot0, vsq0), c.w);
        float d1 = __fadd_rn(fmaf(-2.0f, dot1, vsq1), c.w);
        if (d0 < best0) { best0 = d0; bi0 = n; }   // strict < keeps first index on ties
        if (d1 < best1) { best1 = d1; bi1 = n; }
    }

    mi[(size_t)b * V_PTS + v0] = bi0;
    mi[(size_t)b * V_PTS + v1] = bi1;
}

// ---------------------------------------------------------------------------
// Kernel 2: build hit-mask per graph in LDS (scatter mi), masked-sum a
// 128-residue slice of feats into a partial accumulator.
// Grid: B_GR * SEGS = 256 blocks, 256 threads (h = tid&127, half = tid>>7).
// ---------------------------------------------------------------------------
__global__ __launch_bounds__(256) void k_pool(const int* __restrict__ mi,
                                              const float* __restrict__ feats,
                                              float* __restrict__ partial) {
    __shared__ float msk[N_RES];                        // 8 KB
    __shared__ float red[H_DIM];
    const int b   = blockIdx.x >> 4;
    const int seg = blockIdx.x & (SEGS - 1);

    for (int i = threadIdx.x; i < N_RES; i += 256) msk[i] = 0.0f;
    __syncthreads();

    const int* mib = mi + (size_t)b * V_PTS;
    for (int v = threadIdx.x; v < V_PTS; v += 256) msk[mib[v]] = 1.0f;  // race benign: all write 1
    __syncthreads();

    const int h    = threadIdx.x & (H_DIM - 1);
    const int half = threadIdx.x >> 7;                  // 0..1
    const int n0   = seg * (N_RES / SEGS);              // 128-residue slice
    const float* fb = feats + ((size_t)b * N_RES + n0) * H_DIM;

    float acc = 0.0f;
    for (int n = half; n < N_RES / SEGS; n += 2)
        acc = fmaf(fb[(size_t)n * H_DIM + h], msk[n0 + n], acc);

    if (half) red[h] = acc;
    __syncthreads();
    if (!half)
        partial[((size_t)b * SEGS + seg) * H_DIM + h] = acc + red[h];
}

// ---------------------------------------------------------------------------
// Kernel 3: reduce partials -> pooled[B][H], then pooled@W1+b1 -> relu -> @W2+b2.
// One block, 128 threads. Trivial FLOPs.
// ---------------------------------------------------------------------------
__global__ __launch_bounds__(128) void k_mlp(const float* __restrict__ partial,
                                             const float* __restrict__ W1,
                                             const float* __restrict__ b1,
                                             const float* __restrict__ W2,
                                             const float* __restrict__ b2,
                                             float* __restrict__ out) {
    __shared__ float pooled[B_GR][H_DIM];
    __shared__ float h1[B_GR][H_DIM];
    const int j = threadIdx.x;

    for (int b = 0; b < B_GR; ++b) {
        float s = 0.0f;
        for (int g = 0; g < SEGS; ++g)
            s += partial[((size_t)b * SEGS + g) * H_DIM + j];
        pooled[b][j] = s;
    }
    __syncthreads();

    for (int b = 0; b < B_GR; ++b) {
        float acc = b1[j];
        for (int hh = 0; hh < H_DIM; ++hh)
            acc = fmaf(pooled[b][hh], W1[hh * H_DIM + j], acc);
        h1[b][j] = fmaxf(acc, 0.0f);
    }
    __syncthreads();

    if (j < B_GR * C_OUT) {
        const int b = j / C_OUT, k = j % C_OUT;
        float acc = b2[k];
        for (int hh = 0; hh < H_DIM; ++hh)
            acc = fmaf(h1[b][hh], W2[hh * C_OUT + k], acc);
        out[j] = acc;
    }
}

extern "C" void kernel_launch(void* const* d_in, const int* in_sizes, int n_in,
                              void* d_out, int out_size, void* d_ws, size_t ws_size,
                              hipStream_t stream) {
    const float* verts  = (const float*)d_in[0];   // [B,V,3]
    const float* coords = (const float*)d_in[1];   // [B,N,3]
    const float* feats  = (const float*)d_in[2];   // [B,N,H]
    const float* W1     = (const float*)d_in[3];   // [H,H]
    const float* b1     = (const float*)d_in[4];   // [H]
    const float* W2     = (const float*)d_in[5];   // [H,C_OUT]
    const float* b2     = (const float*)d_in[6];   // [C_OUT]
    float* out = (float*)d_out;                    // [B,C_OUT] = 112 floats

    // workspace layout
    int*   mi      = (int*)d_ws;                                   // B*V ints   = 512 KB
    float* partial = (float*)((char*)d_ws + (size_t)B_GR * V_PTS * sizeof(int)); // B*SEGS*H = 128 KB

    k_argmin<<<B_GR * (V_PTS / 512), 256, 0, stream>>>(verts, coords, mi);
    k_pool  <<<B_GR * SEGS,          256, 0, stream>>>(mi, feats, partial);
    k_mlp   <<<1,                    128, 0, stream>>>(partial, W1, b1, W2, b2, out);
}

// Round 2
// 159.796 us; speedup vs baseline: 1.2470x; 1.2470x over previous
//
#include <hip/hip_runtime.h>
#include <hip/hip_bf16.h>

// Problem constants (fixed by the reference): B=16, V=8192, N=2048, H=128, C_OUT=7
#define B_GR   16
#define V_PTS  8192
#define N_RES  2048
#define H_DIM  128
#define C_OUT  7
#define SEGS   16            // pool kernel: residue segments per graph (128 residues each)

// argmin decomposition
#define NSPLIT 4                     // residue splits per graph
#define NL     (N_RES / NSPLIT)      // 512 residues per block
#define VPT    4                     // vertices per thread (4 independent FMA chains)
#define VBLK   (256 * VPT)           // 1024 vertices per block
#define VBLKS  (V_PTS / VBLK)        // 8 vertex-blocks per graph

// ---------------------------------------------------------------------------
// Kernel 1: partial nearest-residue argmin over a 512-residue slice, 4
// vertices per thread. Bit-exact replication of the reference fp32 sequence:
//   d = fadd( fma(-2, dot, vsq), csq ),  dot = fadd(fadd(x*cx, y*cy), z*cz)
// (fma(-2,dot,vsq) == RN(vsq - 2*dot) exactly since 2*dot is exact.)
// Partials merged across splits with atomicMin on packed
// (monotone-flipped dist bits << 32) | global_idx  — equal dists pick the
// smaller index, matching np.argmin first-occurrence. d == -0.0 impossible
// (csq >= +0), so the flip transform's -0<+0 quirk never triggers.
// Grid: B * VBLKS * NSPLIT = 512 blocks => 2 blocks/CU, 8 waves/CU.
// ---------------------------------------------------------------------------
__global__ __launch_bounds__(256, 2) void k_argmin(const float* __restrict__ verts,
                                                   const float* __restrict__ coords,
                                                   unsigned long long* __restrict__ mi64) {
    __shared__ float4 sc[NL];                          // 8 KB
    const int b  = blockIdx.x / (VBLKS * NSPLIT);
    const int r  = blockIdx.x % (VBLKS * NSPLIT);
    const int vb = r / NSPLIT;
    const int ns = r % NSPLIT;

    const float* cbase = coords + ((size_t)b * N_RES + ns * NL) * 3;
    for (int i = threadIdx.x; i < NL; i += 256) {
        float x = cbase[i * 3 + 0];
        float y = cbase[i * 3 + 1];
        float z = cbase[i * 3 + 2];
        float csq = __fadd_rn(__fadd_rn(__fmul_rn(x, x), __fmul_rn(y, y)), __fmul_rn(z, z));
        sc[i] = make_float4(x, y, z, csq);
    }
    __syncthreads();

    const int vbase = vb * VBLK + threadIdx.x;         // vertex index within graph
    const float* vp = verts + (size_t)b * V_PTS * 3;

    float vx[VPT], vy[VPT], vz[VPT], vsq[VPT], best[VPT];
    int bi[VPT];
#pragma unroll
    for (int k = 0; k < VPT; ++k) {
        const int v = vbase + k * 256;
        vx[k] = vp[v * 3 + 0];
        vy[k] = vp[v * 3 + 1];
        vz[k] = vp[v * 3 + 2];
        vsq[k] = __fadd_rn(__fadd_rn(__fmul_rn(vx[k], vx[k]), __fmul_rn(vy[k], vy[k])),
                           __fmul_rn(vz[k], vz[k]));
        best[k] = 3.402823466e+38f;
        bi[k] = 0;
    }

#pragma unroll 4
    for (int n = 0; n < NL; ++n) {
        const float4 c = sc[n];
#pragma unroll
        for (int k = 0; k < VPT; ++k) {
            float dot = __fadd_rn(__fadd_rn(__fmul_rn(vx[k], c.x), __fmul_rn(vy[k], c.y)),
                                  __fmul_rn(vz[k], c.z));
            float d = __fadd_rn(fmaf(-2.0f, dot, vsq[k]), c.w);
            if (d < best[k]) { best[k] = d; bi[k] = n; }   // strict <: first index wins
        }
    }

#pragma unroll
    for (int k = 0; k < VPT; ++k) {
        unsigned int bits = __float_as_uint(best[k]);
        unsigned int key  = bits ^ (unsigned int)(((int)bits >> 31) | 0x80000000);
        unsigned long long packed =
            ((unsigned long long)key << 32) | (unsigned int)(ns * NL + bi[k]);
        atomicMin(&mi64[(size_t)b * V_PTS + vbase + k * 256], packed);
    }
}

// ---------------------------------------------------------------------------
// Kernel 2: rebuild per-graph hit mask in LDS from packed argmin (low 32 bits
// = index), masked-sum a 128-residue slice of feats with float4 loads.
// Grid: B*SEGS = 256 blocks, 256 threads: lane-quad q=tid&31 covers H=128 as
// float4; slice s=tid>>5 gives 8-way n-parallelism, LDS-reduced at the end.
// ---------------------------------------------------------------------------
__global__ __launch_bounds__(256) void k_pool(const unsigned long long* __restrict__ mi64,
                                              const float* __restrict__ feats,
                                              float* __restrict__ partial) {
    __shared__ float msk[N_RES];                        // 8 KB
    __shared__ float4 red[8][32];
    const int b   = blockIdx.x >> 4;
    const int seg = blockIdx.x & (SEGS - 1);

    for (int i = threadIdx.x; i < N_RES; i += 256) msk[i] = 0.0f;
    __syncthreads();

    const unsigned long long* mb = mi64 + (size_t)b * V_PTS;
    for (int v = threadIdx.x; v < V_PTS; v += 256)
        msk[(unsigned int)mb[v]] = 1.0f;                // race benign: all write 1
    __syncthreads();

    const int q = threadIdx.x & 31;                     // float4 column (h = 4q..4q+3)
    const int s = threadIdx.x >> 5;                     // n-slice 0..7
    const int n0 = seg * (N_RES / SEGS);
    const float4* fb4 = (const float4*)(feats + ((size_t)b * N_RES + n0) * H_DIM);

    float4 acc = make_float4(0.f, 0.f, 0.f, 0.f);
    for (int n = s; n < N_RES / SEGS; n += 8) {
        const float m = msk[n0 + n];
        const float4 f = fb4[(size_t)n * 32 + q];
        acc.x = fmaf(f.x, m, acc.x);
        acc.y = fmaf(f.y, m, acc.y);
        acc.z = fmaf(f.z, m, acc.z);
        acc.w = fmaf(f.w, m, acc.w);
    }
    red[s][q] = acc;
    __syncthreads();

    if (s == 0) {
        float4 t = acc;
#pragma unroll
        for (int i = 1; i < 8; ++i) {
            t.x += red[i][q].x; t.y += red[i][q].y;
            t.z += red[i][q].z; t.w += red[i][q].w;
        }
        ((float4*)partial)[((size_t)b * SEGS + seg) * 32 + q] = t;
    }
}

// ---------------------------------------------------------------------------
// Kernel 3: per-graph block — reduce 16 seg partials -> pooled[H], then
// relu(pooled@W1+b1)@W2+b2 -> out[b][7]. 16 blocks x 128 threads.
// ---------------------------------------------------------------------------
__global__ __launch_bounds__(128) void k_mlp(const float* __restrict__ partial,
                                             const float* __restrict__ W1,
                                             const float* __restrict__ b1,
                                             const float* __restrict__ W2,
                                             const float* __restrict__ b2,
                                             float* __restrict__ out) {
    __shared__ float pooled[H_DIM];
    __shared__ float h1[H_DIM];
    const int b = blockIdx.x;
    const int j = threadIdx.x;

    float s = 0.0f;
#pragma unroll
    for (int g = 0; g < SEGS; ++g)
        s += partial[((size_t)b * SEGS + g) * H_DIM + j];
    pooled[j] = s;
    __syncthreads();

    float acc = b1[j];
    for (int hh = 0; hh < H_DIM; ++hh)
        acc = fmaf(pooled[hh], W1[hh * H_DIM + j], acc);
    h1[j] = fmaxf(acc, 0.0f);
    __syncthreads();

    if (j < C_OUT) {
        float o = b2[j];
        for (int hh = 0; hh < H_DIM; ++hh)
            o = fmaf(h1[hh], W2[hh * C_OUT + j], o);
        out[(size_t)b * C_OUT + j] = o;
    }
}

extern "C" void kernel_launch(void* const* d_in, const int* in_sizes, int n_in,
                              void* d_out, int out_size, void* d_ws, size_t ws_size,
                              hipStream_t stream) {
    const float* verts  = (const float*)d_in[0];   // [B,V,3]
    const float* coords = (const float*)d_in[1];   // [B,N,3]
    const float* feats  = (const float*)d_in[2];   // [B,N,H]
    const float* W1     = (const float*)d_in[3];   // [H,H]
    const float* b1     = (const float*)d_in[4];   // [H]
    const float* W2     = (const float*)d_in[5];   // [H,C_OUT]
    const float* b2     = (const float*)d_in[6];   // [C_OUT]
    float* out = (float*)d_out;                    // [B,C_OUT]

    // workspace layout
    unsigned long long* mi64 = (unsigned long long*)d_ws;                 // B*V u64 = 1 MB
    float* partial = (float*)((char*)d_ws + (size_t)B_GR * V_PTS * 8);    // B*SEGS*H = 128 KB

    hipMemsetAsync(mi64, 0xFF, (size_t)B_GR * V_PTS * 8, stream);         // graph-legal memset node
    k_argmin<<<B_GR * VBLKS * NSPLIT, 256, 0, stream>>>(verts, coords, mi64);
    k_pool  <<<B_GR * SEGS,           256, 0, stream>>>(mi64, feats, partial);
    k_mlp   <<<B_GR,                  128, 0, stream>>>(partial, W1, b1, W2, b2, out);
}

// Round 3
// 149.959 us; speedup vs baseline: 1.3288x; 1.0656x over previous
//
#include <hip/hip_runtime.h>
#include <hip/hip_bf16.h>

// Problem constants (fixed by the reference): B=16, V=8192, N=2048, H=128, C_OUT=7
#define B_GR   16
#define V_PTS  8192
#define N_RES  2048
#define H_DIM  128
#define C_OUT  7
#define SEGS   16            // pool kernel: residue segments per graph (128 residues each)

// argmin decomposition
#define NSPLIT 16                    // residue splits per graph
#define NL     (N_RES / NSPLIT)      // 128 residues per block
#define VPT    8                     // vertices per thread (8 independent FMA chains)
#define VBLK   (256 * VPT)           // 2048 vertices per block
#define VBLKS  (V_PTS / VBLK)        // 4 vertex-blocks per graph
// grid = B * VBLKS * NSPLIT = 16*4*16 = 1024 blocks -> 4 blocks/CU, 16 waves/CU

// ---------------------------------------------------------------------------
// Kernel 1: partial nearest-residue argmin over a 128-residue slice, 8
// vertices per thread. Bit-exact replication of the reference fp32 sequence:
//   d = fadd( fma(-2, dot, vsq), csq ),  dot = fadd(fadd(x*cx, y*cy), z*cz)
// (fma(-2,dot,vsq) == RN(vsq - 2*dot) exactly since 2*dot is exact.)
// Partials merged across splits with atomicMin on packed
// (monotone-flipped dist bits << 32) | global_idx  — equal dists pick the
// smaller index, matching np.argmin first-occurrence. d == -0.0 impossible
// (csq >= +0), so the flip transform's -0<+0 quirk never triggers.
// ---------------------------------------------------------------------------
__global__ __launch_bounds__(256, 4) void k_argmin(const float* __restrict__ verts,
                                                   const float* __restrict__ coords,
                                                   unsigned long long* __restrict__ mi64) {
    __shared__ float4 sc[NL];                          // 2 KB
    const int b  = blockIdx.x / (VBLKS * NSPLIT);
    const int r  = blockIdx.x % (VBLKS * NSPLIT);
    const int vb = r / NSPLIT;
    const int ns = r % NSPLIT;

    const float* cbase = coords + ((size_t)b * N_RES + ns * NL) * 3;
    if (threadIdx.x < NL) {
        const int i = threadIdx.x;
        float x = cbase[i * 3 + 0];
        float y = cbase[i * 3 + 1];
        float z = cbase[i * 3 + 2];
        float csq = __fadd_rn(__fadd_rn(__fmul_rn(x, x), __fmul_rn(y, y)), __fmul_rn(z, z));
        sc[i] = make_float4(x, y, z, csq);
    }
    __syncthreads();

    const int vbase = vb * VBLK + threadIdx.x;         // vertex index within graph
    const float* vp = verts + (size_t)b * V_PTS * 3;

    float vx[VPT], vy[VPT], vz[VPT], vsq[VPT], best[VPT];
    int bi[VPT];
#pragma unroll
    for (int k = 0; k < VPT; ++k) {
        const int v = vbase + k * 256;
        vx[k] = vp[v * 3 + 0];
        vy[k] = vp[v * 3 + 1];
        vz[k] = vp[v * 3 + 2];
        vsq[k] = __fadd_rn(__fadd_rn(__fmul_rn(vx[k], vx[k]), __fmul_rn(vy[k], vy[k])),
                           __fmul_rn(vz[k], vz[k]));
        best[k] = 3.402823466e+38f;
        bi[k] = 0;
    }

    // unroll 2: n stays a uniform (SGPR) value -> cndmask can take it directly,
    // no per-update v_mov of a constant.
#pragma unroll 2
    for (int n = 0; n < NL; ++n) {
        const float4 c = sc[n];
#pragma unroll
        for (int k = 0; k < VPT; ++k) {
            float dot = __fadd_rn(__fadd_rn(__fmul_rn(vx[k], c.x), __fmul_rn(vy[k], c.y)),
                                  __fmul_rn(vz[k], c.z));
            float d = __fadd_rn(fmaf(-2.0f, dot, vsq[k]), c.w);
            bool m = d < best[k];                      // strict <: first index wins
            best[k] = m ? d : best[k];
            bi[k]   = m ? n : bi[k];
        }
    }

#pragma unroll
    for (int k = 0; k < VPT; ++k) {
        unsigned int bits = __float_as_uint(best[k]);
        unsigned int key  = bits ^ (unsigned int)(((int)bits >> 31) | 0x80000000);
        unsigned long long packed =
            ((unsigned long long)key << 32) | (unsigned int)(ns * NL + bi[k]);
        atomicMin(&mi64[(size_t)b * V_PTS + vbase + k * 256], packed);
    }
}

// ---------------------------------------------------------------------------
// Kernel 2: rebuild per-graph hit mask in LDS from packed argmin (low 32 bits
// = index), masked-sum a 128-residue slice of feats with float4 loads.
// Grid: B*SEGS = 256 blocks, 256 threads: lane-quad q=tid&31 covers H=128 as
// float4; slice s=tid>>5 gives 8-way n-parallelism, LDS-reduced at the end.
// ---------------------------------------------------------------------------
__global__ __launch_bounds__(256) void k_pool(const unsigned long long* __restrict__ mi64,
                                              const float* __restrict__ feats,
                                              float* __restrict__ partial) {
    __shared__ float msk[N_RES];                        // 8 KB
    __shared__ float4 red[8][32];
    const int b   = blockIdx.x >> 4;
    const int seg = blockIdx.x & (SEGS - 1);

    for (int i = threadIdx.x; i < N_RES; i += 256) msk[i] = 0.0f;
    __syncthreads();

    const unsigned long long* mb = mi64 + (size_t)b * V_PTS;
    for (int v = threadIdx.x; v < V_PTS; v += 256)
        msk[(unsigned int)mb[v]] = 1.0f;                // race benign: all write 1
    __syncthreads();

    const int q = threadIdx.x & 31;                     // float4 column (h = 4q..4q+3)
    const int s = threadIdx.x >> 5;                     // n-slice 0..7
    const int n0 = seg * (N_RES / SEGS);
    const float4* fb4 = (const float4*)(feats + ((size_t)b * N_RES + n0) * H_DIM);

    float4 acc = make_float4(0.f, 0.f, 0.f, 0.f);
#pragma unroll
    for (int n = 0; n < N_RES / SEGS / 8; ++n) {
        const int nn = s + n * 8;
        const float m = msk[n0 + nn];
        const float4 f = fb4[(size_t)nn * 32 + q];
        acc.x = fmaf(f.x, m, acc.x);
        acc.y = fmaf(f.y, m, acc.y);
        acc.z = fmaf(f.z, m, acc.z);
        acc.w = fmaf(f.w, m, acc.w);
    }
    red[s][q] = acc;
    __syncthreads();

    if (s == 0) {
        float4 t = acc;
#pragma unroll
        for (int i = 1; i < 8; ++i) {
            t.x += red[i][q].x; t.y += red[i][q].y;
            t.z += red[i][q].z; t.w += red[i][q].w;
        }
        ((float4*)partial)[((size_t)b * SEGS + seg) * 32 + q] = t;
    }
}

// ---------------------------------------------------------------------------
// Kernel 3: per-graph block — reduce 16 seg partials -> pooled[H], then
// relu(pooled@W1+b1)@W2+b2 -> out[b][7]. 16 blocks x 128 threads.
// ---------------------------------------------------------------------------
__global__ __launch_bounds__(128) void k_mlp(const float* __restrict__ partial,
                                             const float* __restrict__ W1,
                                             const float* __restrict__ b1,
                                             const float* __restrict__ W2,
                                             const float* __restrict__ b2,
                                             float* __restrict__ out) {
    __shared__ float pooled[H_DIM];
    __shared__ float h1[H_DIM];
    const int b = blockIdx.x;
    const int j = threadIdx.x;

    float s = 0.0f;
#pragma unroll
    for (int g = 0; g < SEGS; ++g)
        s += partial[((size_t)b * SEGS + g) * H_DIM + j];
    pooled[j] = s;
    __syncthreads();

    float acc = b1[j];
#pragma unroll 8
    for (int hh = 0; hh < H_DIM; ++hh)
        acc = fmaf(pooled[hh], W1[hh * H_DIM + j], acc);
    h1[j] = fmaxf(acc, 0.0f);
    __syncthreads();

    if (j < C_OUT) {
        float o = b2[j];
#pragma unroll 8
        for (int hh = 0; hh < H_DIM; ++hh)
            o = fmaf(h1[hh], W2[hh * C_OUT + j], o);
        out[(size_t)b * C_OUT + j] = o;
    }
}

extern "C" void kernel_launch(void* const* d_in, const int* in_sizes, int n_in,
                              void* d_out, int out_size, void* d_ws, size_t ws_size,
                              hipStream_t stream) {
    const float* verts  = (const float*)d_in[0];   // [B,V,3]
    const float* coords = (const float*)d_in[1];   // [B,N,3]
    const float* feats  = (const float*)d_in[2];   // [B,N,H]
    const float* W1     = (const float*)d_in[3];   // [H,H]
    const float* b1     = (const float*)d_in[4];   // [H]
    const float* W2     = (const float*)d_in[5];   // [H,C_OUT]
    const float* b2     = (const float*)d_in[6];   // [C_OUT]
    float* out = (float*)d_out;                    // [B,C_OUT]

    // workspace layout
    unsigned long long* mi64 = (unsigned long long*)d_ws;                 // B*V u64 = 1 MB
    float* partial = (float*)((char*)d_ws + (size_t)B_GR * V_PTS * 8);    // B*SEGS*H = 128 KB

    hipMemsetAsync(mi64, 0xFF, (size_t)B_GR * V_PTS * 8, stream);         // graph-legal memset node
    k_argmin<<<B_GR * VBLKS * NSPLIT, 256, 0, stream>>>(verts, coords, mi64);
    k_pool  <<<B_GR * SEGS,           256, 0, stream>>>(mi64, feats, partial);
    k_mlp   <<<B_GR,                  128, 0, stream>>>(partial, W1, b1, W2, b2, out);
}